// Round 3
// baseline (78.465 us; speedup 1.0000x reference)
//
#include <hip/hip_runtime.h>
#include <cmath>
#include <complex>

// ChebyDecimate: 8th-order Chebyshev-I lowpass (4 cascaded biquads, DF2T,
// zero init state) + decimate-by-2.  x: [32, 131072] f32 -> out: [32, 65536] f32.
//
// Strategy: overlap-save block parallelism. Slowest pole |p| = 0.9329
// => impulse response decays 0.9329^192 ~ 1.6e-6 over H=192 samples.
// Each thread owns L=64 output samples and runs the cascade from zero state
// starting H samples early; warm-up outputs discarded. Chunks near t=0 feed
// zeros (bit-exact vs reference zero init). 65536 threads = 1024 waves =
// 1 wave/SIMD, VALU-issue-bound (~20 VALU/sample).

#define T_LEN   131072
#define B_ROWS  32
#define L_CHUNK 64
#define H_WARM  192
#define CPR     (T_LEN / L_CHUNK)        /* 2048 chunks per row */
#define NTHREADS (B_ROWS * CPR)          /* 65536 */

struct Coef { float g; float a1[4]; float a2[4]; };

__device__ __forceinline__ float4 ldg4(const float* __restrict__ p, int idx) {
    // idx is always a multiple of 4 and either fully <0 or fully in-range.
    if (idx >= 0) return *reinterpret_cast<const float4*>(p + idx);
    return make_float4(0.f, 0.f, 0.f, 0.f);
}

__global__ __launch_bounds__(256) void cheby_decimate_kernel(
    const float* __restrict__ x, float* __restrict__ out, Coef c)
{
    const int tid   = blockIdx.x * blockDim.x + threadIdx.x;
    const int row   = tid >> 11;              // / CPR
    const int chunk = tid & (CPR - 1);
    const float* __restrict__ xr = x + (size_t)row * T_LEN;
    float* __restrict__ orow = out + (size_t)row * (T_LEN / 2)
                                   + (size_t)chunk * (L_CHUNK / 2);

    const float g    = c.g;                    // b0 = b2 = g, b1 = 2g (all sections)
    const float na10 = -c.a1[0], na20 = -c.a2[0];
    const float na11 = -c.a1[1], na21 = -c.a2[1];
    const float na12 = -c.a1[2], na22 = -c.a2[2];
    const float na13 = -c.a1[3], na23 = -c.a2[3];

    float z11=0.f,z12=0.f, z21=0.f,z22=0.f, z31=0.f,z32=0.f, z41=0.f,z42=0.f;

    const int start = chunk * L_CHUNK - H_WARM;

    // DF2T biquad cascade, one sample. 5 VALU per section:
    //   w = g*y; out = w + z1; z1' = 2w + z2 - a1*out; z2' = w - a2*out
#define STEP(yv) do {                                                          \
        float y = (yv); float w, o, t;                                         \
        w = g*y; o = w + z11; t = fmaf(2.f, w, z12);                           \
        z11 = fmaf(na10, o, t); z12 = fmaf(na20, o, w); y = o;                 \
        w = g*y; o = w + z21; t = fmaf(2.f, w, z22);                           \
        z21 = fmaf(na11, o, t); z22 = fmaf(na21, o, w); y = o;                 \
        w = g*y; o = w + z31; t = fmaf(2.f, w, z32);                           \
        z31 = fmaf(na12, o, t); z32 = fmaf(na22, o, w); y = o;                 \
        w = g*y; o = w + z41; t = fmaf(2.f, w, z42);                           \
        z41 = fmaf(na13, o, t); z42 = fmaf(na23, o, w); y = o;                 \
        (yv) = y;                                                              \
    } while (0)

    // ---- warm-up: H_WARM samples, outputs discarded ----
    float4 cur = ldg4(xr, start);
    #pragma unroll 4
    for (int gb = 0; gb < H_WARM / 4; ++gb) {
        float4 nxt = ldg4(xr, start + 4 * (gb + 1));   // prefetch next group
        STEP(cur.x); STEP(cur.y); STEP(cur.z); STEP(cur.w);
        cur = nxt;
    }

    // ---- live region: L_CHUNK samples, keep even-index outputs ----
    #pragma unroll
    for (int gb = 0; gb < L_CHUNK / 4; ++gb) {
        float4 nxt = make_float4(0.f, 0.f, 0.f, 0.f);
        if (gb + 1 < L_CHUNK / 4)
            nxt = ldg4(xr, start + 4 * (H_WARM / 4 + gb + 1));
        STEP(cur.x); STEP(cur.y); STEP(cur.z); STEP(cur.w);
        reinterpret_cast<float2*>(orow)[gb] = make_float2(cur.x, cur.z);
        cur = nxt;
    }
#undef STEP
}

extern "C" void kernel_launch(void* const* d_in, const int* in_sizes, int n_in,
                              void* d_out, int out_size, void* d_ws, size_t ws_size,
                              hipStream_t stream)
{
    const float* x = (const float*)d_in[0];
    float* out = (float*)d_out;

    // cheby1(N=8, rp=0.05dB, Wn=0.5) SOS design in f64, exactly mirroring the
    // reference's math, then cast to f32 like jnp.asarray(..., float32).
    const int N = 8;
    const double rp = 0.05;
    const double eps = std::sqrt(std::pow(10.0, rp / 10.0) - 1.0);
    const double mu  = std::asinh(1.0 / eps) / N;

    std::complex<double> p[8];
    std::complex<double> prodnp(1.0, 0.0);
    for (int i = 0; i < N; ++i) {
        double theta = M_PI * (2.0 * (i + 1) - 1.0) / (2.0 * N);
        p[i] = std::complex<double>(-std::sinh(mu) * std::sin(theta),
                                     std::cosh(mu) * std::cos(theta));
        prodnp *= -p[i];
    }
    double gain = prodnp.real() / std::sqrt(1.0 + eps * eps);  // N even

    const double fs = 2.0;
    const double warped = 2.0 * fs * std::tan(M_PI * 0.5 / fs);  // = 4
    std::complex<double> prodden(1.0, 0.0);
    std::complex<double> pz[8];
    for (int i = 0; i < N; ++i) {
        p[i] *= warped;
        pz[i] = (2.0 * fs + p[i]) / (2.0 * fs - p[i]);
        prodden *= (2.0 * fs - p[i]);
    }
    gain *= std::pow(warped, (double)N);
    gain /= prodden.real();

    Coef c;
    int ns = 0;
    double A1[4], A2[4];
    for (int i = 0; i < N; ++i) {
        if (pz[i].imag() > 0.0) {
            A1[ns] = -2.0 * pz[i].real();
            A2[ns] = std::norm(pz[i]);
            ++ns;
        }
    }
    const double gsec = std::pow(gain, 1.0 / ns);
    c.g = (float)gsec;
    for (int s = 0; s < 4; ++s) { c.a1[s] = (float)A1[s]; c.a2[s] = (float)A2[s]; }

    dim3 block(256), grid(NTHREADS / 256);
    hipLaunchKernelGGL(cheby_decimate_kernel, grid, block, 0, stream, x, out, c);
}

// Round 6
// 74.910 us; speedup vs baseline: 1.0474x; 1.0474x over previous
//
#include <hip/hip_runtime.h>
#include <cmath>
#include <complex>

// ChebyDecimate: 8th-order Chebyshev-I lowpass (4 cascaded biquads, DF2T,
// zero init state) + decimate-by-2.  x: [32, 131072] f32 -> out: [32, 65536] f32.
//
// v2: overlap-save (H=192 warm-up, |p|_max=0.9329 -> truncation ~1.6e-6) with
// LDS-staged I/O. v1 read/wrote at 256B lane stride (64 cache lines per wave
// load; ~28us kernel). Now: block stages its 16576-float window into LDS
// coalesced, threads read ds_read_b128 with XOR-swizzle (even bank spread),
// outputs transpose through LDS for coalesced float4 stores.

#define T_LEN   131072
#define B_ROWS  32
#define OUT_LEN (T_LEN / 2)
#define L_CHUNK 64
#define H_WARM  192
#define TPB     256
#define BLOCKS_PER_ROW (T_LEN / (L_CHUNK * TPB))      /* 8 */
#define WIN_FLOATS (TPB * L_CHUNK + H_WARM)           /* 16576 */
#define WIN_UNITS  (WIN_FLOATS / 4)                   /* 4144 float4s = 66.3KB */
#define NBLOCKS (B_ROWS * BLOCKS_PER_ROW)             /* 256 */

struct Coef { float g; float a1[4]; float a2[4]; };

__global__ __launch_bounds__(256) void cheby_decimate_kernel(
    const float* __restrict__ x, float* __restrict__ out, Coef c)
{
    __shared__ float4 lds[WIN_UNITS];
    const int t   = threadIdx.x;
    const int row = blockIdx.x / BLOCKS_PER_ROW;
    const int bc  = blockIdx.x % BLOCKS_PER_ROW;
    const float* __restrict__ xr = x + (size_t)row * T_LEN;
    const int wstart = bc * (TPB * L_CHUNK) - H_WARM;   // first float of window

    // ---- coalesced global -> LDS staging, XOR-swizzled on 16B units ----
    // unit w holds window floats [4w,4w+4); stored at w ^ ((w>>4)&7) so that
    // compute-phase reads (stride 16 units/lane) spread evenly over banks.
    #pragma unroll
    for (int k = 0; k < (WIN_UNITS + TPB - 1) / TPB; ++k) {
        int w = t + TPB * k;
        if (w < WIN_UNITS) {
            int g = wstart + 4 * w;                     // aligned, mult of 4
            float4 v = make_float4(0.f, 0.f, 0.f, 0.f); // g<0: zero init state
            if (g >= 0) v = *reinterpret_cast<const float4*>(xr + g);
            lds[w ^ ((w >> 4) & 7)] = v;
        }
    }
    __syncthreads();

    const float g0   = c.g;                    // b0 = b2 = g, b1 = 2g
    const float na10 = -c.a1[0], na20 = -c.a2[0];
    const float na11 = -c.a1[1], na21 = -c.a2[1];
    const float na12 = -c.a1[2], na22 = -c.a2[2];
    const float na13 = -c.a1[3], na23 = -c.a2[3];

    float z11=0.f,z12=0.f, z21=0.f,z22=0.f, z31=0.f,z32=0.f, z41=0.f,z42=0.f;

#define LREAD(u) lds[(u) ^ (((u) >> 4) & 7)]
#define STEP(yv) do {                                                          \
        float y = (yv); float w_, o, tt;                                       \
        w_ = g0*y; o = w_ + z11; tt = fmaf(2.f, w_, z12);                      \
        z11 = fmaf(na10, o, tt); z12 = fmaf(na20, o, w_); y = o;               \
        w_ = g0*y; o = w_ + z21; tt = fmaf(2.f, w_, z22);                      \
        z21 = fmaf(na11, o, tt); z22 = fmaf(na21, o, w_); y = o;               \
        w_ = g0*y; o = w_ + z31; tt = fmaf(2.f, w_, z32);                      \
        z31 = fmaf(na12, o, tt); z32 = fmaf(na22, o, w_); y = o;               \
        w_ = g0*y; o = w_ + z41; tt = fmaf(2.f, w_, z42);                      \
        z41 = fmaf(na13, o, tt); z42 = fmaf(na23, o, w_); y = o;               \
        (yv) = y;                                                              \
    } while (0)

    // thread t's window: buffer units 16t .. 16t+63 (256 samples)
    const int ub = 16 * t;
    float4 cur = LREAD(ub);
    float outv[32];

    // warm-up: 192 samples, outputs discarded
    #pragma unroll 4
    for (int j = 0; j < 48; ++j) {
        float4 nxt = LREAD(ub + j + 1);
        STEP(cur.x); STEP(cur.y); STEP(cur.z); STEP(cur.w);
        cur = nxt;
    }
    // live: 64 samples, keep even-index outputs (statically indexed regs)
    #pragma unroll
    for (int j = 48; j < 64; ++j) {
        float4 nxt = (j < 63) ? LREAD(ub + j + 1) : make_float4(0.f,0.f,0.f,0.f);
        STEP(cur.x); STEP(cur.y); STEP(cur.z); STEP(cur.w);
        outv[2*(j-48)]   = cur.x;
        outv[2*(j-48)+1] = cur.z;
        cur = nxt;
    }
#undef STEP
#undef LREAD

    // ---- outputs -> LDS (swizzled) -> coalesced float4 stores ----
    __syncthreads();   // everyone done reading the staging buffer
    #pragma unroll
    for (int q = 0; q < 8; ++q) {   // unit o = 8t+q, swz: o ^ ((o>>3)&7)
        lds[8*t + (q ^ (t & 7))] =
            make_float4(outv[4*q], outv[4*q+1], outv[4*q+2], outv[4*q+3]);
    }
    __syncthreads();
    const size_t obase = (size_t)row * OUT_LEN + (size_t)bc * (TPB * L_CHUNK / 2);
    #pragma unroll
    for (int k = 0; k < 8; ++k) {
        int v = t + TPB * k;        // 2048 units total
        float4 d = lds[(v & ~7) + ((v & 7) ^ ((v >> 3) & 7))];
        *reinterpret_cast<float4*>(out + obase + 4 * v) = d;
    }
}

extern "C" void kernel_launch(void* const* d_in, const int* in_sizes, int n_in,
                              void* d_out, int out_size, void* d_ws, size_t ws_size,
                              hipStream_t stream)
{
    const float* x = (const float*)d_in[0];
    float* out = (float*)d_out;

    // cheby1(N=8, rp=0.05dB, Wn=0.5) SOS design in f64, exactly mirroring the
    // reference's math, then cast to f32 like jnp.asarray(..., float32).
    const int N = 8;
    const double rp = 0.05;
    const double eps = std::sqrt(std::pow(10.0, rp / 10.0) - 1.0);
    const double mu  = std::asinh(1.0 / eps) / N;

    std::complex<double> p[8];
    std::complex<double> prodnp(1.0, 0.0);
    for (int i = 0; i < N; ++i) {
        double theta = M_PI * (2.0 * (i + 1) - 1.0) / (2.0 * N);
        p[i] = std::complex<double>(-std::sinh(mu) * std::sin(theta),
                                     std::cosh(mu) * std::cos(theta));
        prodnp *= -p[i];
    }
    double gain = prodnp.real() / std::sqrt(1.0 + eps * eps);  // N even

    const double fs = 2.0;
    const double warped = 2.0 * fs * std::tan(M_PI * 0.5 / fs);  // = 4
    std::complex<double> prodden(1.0, 0.0);
    std::complex<double> pz[8];
    for (int i = 0; i < N; ++i) {
        p[i] *= warped;
        pz[i] = (2.0 * fs + p[i]) / (2.0 * fs - p[i]);
        prodden *= (2.0 * fs - p[i]);
    }
    gain *= std::pow(warped, (double)N);
    gain /= prodden.real();

    Coef c;
    int ns = 0;
    double A1[4], A2[4];
    for (int i = 0; i < N; ++i) {
        if (pz[i].imag() > 0.0) {
            A1[ns] = -2.0 * pz[i].real();
            A2[ns] = std::norm(pz[i]);
            ++ns;
        }
    }
    const double gsec = std::pow(gain, 1.0 / ns);
    c.g = (float)gsec;
    for (int s = 0; s < 4; ++s) { c.a1[s] = (float)A1[s]; c.a2[s] = (float)A2[s]; }

    dim3 block(TPB), grid(NBLOCKS);
    hipLaunchKernelGGL(cheby_decimate_kernel, grid, block, 0, stream, x, out, c);
}

// Round 7
// 71.501 us; speedup vs baseline: 1.0974x; 1.0477x over previous
//
#include <hip/hip_runtime.h>
#include <cmath>
#include <complex>

// ChebyDecimate: 8th-order Chebyshev-I lowpass (4 cascaded biquads, DF2T,
// zero init state) + decimate-by-2.  x: [32, 131072] f32 -> out: [32, 65536] f32.
//
// v3: overlap-save, H=128 (tail std ~1e-4 << 7.8e-3 rounding floor), with the
// 4 sections SOFTWARE-PIPELINED across samples: section s processes sample
// n-s+1, so the inter-sample dependency chain is 2 ops (8 cyc) instead of
// 8 ops (32 cyc). Same fmaf DAG per sample => bit-identical to cascade.
// LDS-staged coalesced I/O (XOR-swizzled) as v2.

#define T_LEN   131072
#define B_ROWS  32
#define OUT_LEN (T_LEN / 2)
#define L_CHUNK 64
#define H_WARM  128
#define TPB     256
#define BLOCKS_PER_ROW (T_LEN / (L_CHUNK * TPB))      /* 8 */
#define WIN_FLOATS (TPB * L_CHUNK + H_WARM)           /* 16512 */
#define WIN_UNITS  (WIN_FLOATS / 4)                   /* 4128 float4s */
#define LDS_UNITS  (WIN_UNITS + 8)                    /* +8 zero pad units */
#define NBLOCKS (B_ROWS * BLOCKS_PER_ROW)             /* 256 */

struct Coef { float g; float a1[4]; float a2[4]; };

__global__ __launch_bounds__(256) void cheby_decimate_kernel(
    const float* __restrict__ x, float* __restrict__ out, Coef c)
{
    __shared__ float4 lds[LDS_UNITS];
    const int t   = threadIdx.x;
    const int row = blockIdx.x / BLOCKS_PER_ROW;
    const int bc  = blockIdx.x % BLOCKS_PER_ROW;
    const float* __restrict__ xr = x + (size_t)row * T_LEN;
    const int wstart = bc * (TPB * L_CHUNK) - H_WARM;   // first float of window

    // ---- coalesced global -> LDS staging, XOR-swizzled on 16B units ----
    // swizzle permutes within 8-unit groups: u' = u ^ ((u>>4)&7)
    #pragma unroll
    for (int k = 0; k < (WIN_UNITS + TPB - 1) / TPB; ++k) {
        int w = t + TPB * k;
        if (w < WIN_UNITS) {
            int g = wstart + 4 * w;                     // aligned, mult of 4
            float4 v = make_float4(0.f, 0.f, 0.f, 0.f); // g<0: zero init state
            if (g >= 0) v = *reinterpret_cast<const float4*>(xr + g);
            lds[w ^ ((w >> 4) & 7)] = v;
        }
    }
    if (t < 8)  // zero the pad group (consumed only by discarded tail outputs)
        lds[WIN_UNITS + t] = make_float4(0.f, 0.f, 0.f, 0.f);
    __syncthreads();

    const float g0   = c.g;                    // b0 = b2 = g, b1 = 2g
    const float na10 = -c.a1[0], na20 = -c.a2[0];
    const float na11 = -c.a1[1], na21 = -c.a2[1];
    const float na12 = -c.a1[2], na22 = -c.a2[2];
    const float na13 = -c.a1[3], na23 = -c.a2[3];

    float z11=0.f,z12=0.f, z21=0.f,z22=0.f, z31=0.f,z32=0.f, z41=0.f,z42=0.f;
    float y1=0.f, y2=0.f, y3=0.f;   // pipeline delay regs (3 leading zeros)

#define LREAD(u) lds[(u) ^ (((u) >> 4) & 7)]
#define SEC(yin, z1, z2, na1, na2, oo) do {                                    \
        float w_ = g0 * (yin); oo = w_ + z1;                                   \
        z1 = fmaf(na1, oo, fmaf(2.f, w_, z2)); z2 = fmaf(na2, oo, w_);         \
    } while (0)
    // one pipelined iteration: all 4 sections independent within the iter
#define PSTEP(xi, STORE) do {                                                  \
        float o1, o2, o3, o4;                                                  \
        SEC((xi), z11, z12, na10, na20, o1);                                   \
        SEC(y1,   z21, z22, na11, na21, o2);                                   \
        SEC(y2,   z31, z32, na12, na22, o3);                                   \
        SEC(y3,   z41, z42, na13, na23, o4);                                   \
        y1 = o1; y2 = o2; y3 = o3; STORE;                                      \
    } while (0)

    // thread t: window floats [64t, 64t+192) = units [16t, 16t+48)
    const int ub = 16 * t;
    float4 cur = LREAD(ub);
    float outv[32];

    // warm-up: groups m=0..31 (samples 0..127 emerge; none live)
    #pragma unroll 4
    for (int m = 0; m < 32; ++m) {
        float4 nxt = LREAD(ub + m + 1);
        PSTEP(cur.x, (void)0); PSTEP(cur.y, (void)0);
        PSTEP(cur.z, (void)0); PSTEP(cur.w, (void)0);
        cur = nxt;
    }
    // live: groups m=32..48; o4 at i=4m+1 is sample 4m-2, at i=4m+3 sample 4m
    #pragma unroll
    for (int m = 32; m <= 48; ++m) {
        float4 nxt = (m < 48) ? LREAD(ub + m + 1)
                              : make_float4(0.f, 0.f, 0.f, 0.f);
        PSTEP(cur.x, (void)0);
        PSTEP(cur.y, if (m >= 33) outv[2*m - 65] = o4);
        PSTEP(cur.z, (void)0);
        PSTEP(cur.w, if (m <= 47) outv[2*m - 64] = o4);
        cur = nxt;
    }
#undef PSTEP
#undef SEC
#undef LREAD

    // ---- outputs -> LDS (swizzled) -> coalesced float4 stores ----
    __syncthreads();   // everyone done reading the staging buffer
    #pragma unroll
    for (int q = 0; q < 8; ++q) {   // unit o = 8t+q, swz within 8-group
        lds[8*t + (q ^ (t & 7))] =
            make_float4(outv[4*q], outv[4*q+1], outv[4*q+2], outv[4*q+3]);
    }
    __syncthreads();
    const size_t obase = (size_t)row * OUT_LEN + (size_t)bc * (TPB * L_CHUNK / 2);
    #pragma unroll
    for (int k = 0; k < 8; ++k) {
        int v = t + TPB * k;        // 2048 units total
        float4 d = lds[(v & ~7) + ((v & 7) ^ ((v >> 3) & 7))];
        *reinterpret_cast<float4*>(out + obase + 4 * v) = d;
    }
}

extern "C" void kernel_launch(void* const* d_in, const int* in_sizes, int n_in,
                              void* d_out, int out_size, void* d_ws, size_t ws_size,
                              hipStream_t stream)
{
    const float* x = (const float*)d_in[0];
    float* out = (float*)d_out;

    // cheby1(N=8, rp=0.05dB, Wn=0.5) SOS design in f64, exactly mirroring the
    // reference's math, then cast to f32 like jnp.asarray(..., float32).
    const int N = 8;
    const double rp = 0.05;
    const double eps = std::sqrt(std::pow(10.0, rp / 10.0) - 1.0);
    const double mu  = std::asinh(1.0 / eps) / N;

    std::complex<double> p[8];
    std::complex<double> prodnp(1.0, 0.0);
    for (int i = 0; i < N; ++i) {
        double theta = M_PI * (2.0 * (i + 1) - 1.0) / (2.0 * N);
        p[i] = std::complex<double>(-std::sinh(mu) * std::sin(theta),
                                     std::cosh(mu) * std::cos(theta));
        prodnp *= -p[i];
    }
    double gain = prodnp.real() / std::sqrt(1.0 + eps * eps);  // N even

    const double fs = 2.0;
    const double warped = 2.0 * fs * std::tan(M_PI * 0.5 / fs);  // = 4
    std::complex<double> prodden(1.0, 0.0);
    std::complex<double> pz[8];
    for (int i = 0; i < N; ++i) {
        p[i] *= warped;
        pz[i] = (2.0 * fs + p[i]) / (2.0 * fs - p[i]);
        prodden *= (2.0 * fs - p[i]);
    }
    gain *= std::pow(warped, (double)N);
    gain /= prodden.real();

    Coef c;
    int ns = 0;
    double A1[4], A2[4];
    for (int i = 0; i < N; ++i) {
        if (pz[i].imag() > 0.0) {
            A1[ns] = -2.0 * pz[i].real();
            A2[ns] = std::norm(pz[i]);
            ++ns;
        }
    }
    const double gsec = std::pow(gain, 1.0 / ns);
    c.g = (float)gsec;
    for (int s = 0; s < 4; ++s) { c.a1[s] = (float)A1[s]; c.a2[s] = (float)A2[s]; }

    dim3 block(TPB), grid(NBLOCKS);
    hipLaunchKernelGGL(cheby_decimate_kernel, grid, block, 0, stream, x, out, c);
}